// Round 2
// baseline (694.548 us; speedup 1.0000x reference)
//
#include <hip/hip_runtime.h>

#define C_FEAT 128
#define C_EDGE 32
#define K1 288

typedef __attribute__((ext_vector_type(8))) short bf16x8;
typedef __attribute__((ext_vector_type(4))) float f32x4;

__device__ __forceinline__ short f2bf(float x) {
    union { float f; unsigned u; } v; v.f = x;
    unsigned r = v.u + 0x7fffu + ((v.u >> 16) & 1u);   // RTN-even
    return (short)(r >> 16);
}
__device__ __forceinline__ float b2f(short s) {
    union { float f; unsigned u; } v; v.u = ((unsigned)(unsigned short)s) << 16;
    return v.f;
}
__device__ __forceinline__ bf16x8 cvt8(float4 a, float4 b) {
    bf16x8 r;
    r[0] = f2bf(a.x); r[1] = f2bf(a.y); r[2] = f2bf(a.z); r[3] = f2bf(a.w);
    r[4] = f2bf(b.x); r[5] = f2bf(b.y); r[6] = f2bf(b.z); r[7] = f2bf(b.w);
    return r;
}

// ---------------- weight packing (new path) ----------------
// B-fragment layout: wp[((k>>3)*F + f)*8 + (k&7)] so 8 consecutive k for a
// fixed f is one 16B load per lane.
__global__ void prep_w2(const float* __restrict__ We1, const float* __restrict__ We2,
                        short* __restrict__ w1abp, short* __restrict__ w1cp,
                        short* __restrict__ w2p) {
    int idx = blockIdx.x * 256 + threadIdx.x;
    if (idx < 128 * 256) {              // [W1a | W1b]: K=128, F=256
        int k = idx >> 8, f = idx & 255;
        float v = (f < 128) ? We1[k * 128 + f] : We1[(128 + k) * 128 + (f - 128)];
        w1abp[(((k >> 3) * 256 + f) << 3) + (k & 7)] = f2bf(v);
    }
    if (idx < 32 * 128) {               // W1c: K=32, F=128
        int k = idx >> 7, f = idx & 127;
        w1cp[(((k >> 3) * 128 + f) << 3) + (k & 7)] = f2bf(We1[(256 + k) * 128 + f]);
    }
    if (idx < 128 * 128) {              // We2
        int k = idx >> 7, f = idx & 127;
        w2p[(((k >> 3) * 128 + f) << 3) + (k & 7)] = f2bf(We2[k * 128 + f]);
    }
}

// ---------------- counting sort by ej ----------------
__global__ void k_zero(int* __restrict__ hist, int N) {
    int i = blockIdx.x * 256 + threadIdx.x;
    if (i < N) hist[i] = 0;
}
__global__ void k_hist(const int* __restrict__ ej, int* __restrict__ hist, int E) {
    int e = blockIdx.x * 256 + threadIdx.x;
    if (e < E) atomicAdd(&hist[ej[e]], 1);
}
__global__ void k_red(const int* __restrict__ hist, int* __restrict__ part, int N) {
    __shared__ int s[512];
    int t = threadIdx.x, i = blockIdx.x * 512 + t;
    s[t] = i < N ? hist[i] : 0;
    __syncthreads();
    for (int o = 256; o > 0; o >>= 1) {
        if (t < o) s[t] += s[t + o];
        __syncthreads();
    }
    if (t == 0) part[blockIdx.x] = s[0];
}
__global__ void k_scanpart(int* __restrict__ part, int nb) {
    if (threadIdx.x == 0 && blockIdx.x == 0) {
        int a = 0;
        for (int i = 0; i < nb; ++i) { int v = part[i]; part[i] = a; a += v; }
    }
}
__global__ void k_scanblk(const int* __restrict__ hist, const int* __restrict__ part,
                          int* __restrict__ woff, int N) {
    __shared__ int s[512];
    int t = threadIdx.x, i = blockIdx.x * 512 + t;
    int v = i < N ? hist[i] : 0;
    s[t] = v;
    __syncthreads();
    for (int o = 1; o < 512; o <<= 1) {
        int x = (t >= o) ? s[t - o] : 0;
        __syncthreads();
        s[t] += x;
        __syncthreads();
    }
    if (i < N) woff[i] = part[blockIdx.x] + s[t] - v;   // exclusive
}
__global__ void k_perm(const int* __restrict__ ei, const int* __restrict__ ej,
                       int* __restrict__ woff, int* __restrict__ ei_s,
                       int* __restrict__ ej_s, int* __restrict__ eperm, int E) {
    int e = blockIdx.x * 256 + threadIdx.x;
    if (e < E) {
        int t = ej[e];
        int pos = atomicAdd(&woff[t], 1);
        ei_s[pos] = ei[e];
        ej_s[pos] = t;
        eperm[pos] = e;
    }
}

// ---------------- P = ea@W1c + be1 (sorted order, bf16), once ----------------
__global__ __launch_bounds__(256) void p_mfma(const float* __restrict__ ea,
                                              const int* __restrict__ eperm,
                                              const short* __restrict__ w1cp,
                                              const float* __restrict__ be1,
                                              short* __restrict__ P, int E) {
    const int tid = threadIdx.x, wave = tid >> 6, lane = tid & 63;
    const int l15 = lane & 15, q = lane >> 4;
    const int ewave = blockIdx.x * 64 + wave * 16;
    const int eg = ewave + l15;
    const int egc = eg < E ? eg : E - 1;
    const int esrc = eperm[egc];
    const float* asrc = ea + (size_t)esrc * C_EDGE + q * 8;
    float4 a0 = ((const float4*)asrc)[0];
    float4 a1 = ((const float4*)asrc)[1];
    bf16x8 af = cvt8(a0, a1);
    f32x4 acc[8];
#pragma unroll
    for (int nt = 0; nt < 8; ++nt) acc[nt] = (f32x4){0.f, 0.f, 0.f, 0.f};
    const short* bb = w1cp + (q * C_FEAT) * 8;
#pragma unroll
    for (int nt = 0; nt < 8; ++nt) {
        bf16x8 bf = *(const bf16x8*)(bb + (nt * 16 + l15) * 8);
        acc[nt] = __builtin_amdgcn_mfma_f32_16x16x32_bf16(af, bf, acc[nt], 0, 0, 0);
    }
#pragma unroll
    for (int rr = 0; rr < 4; ++rr) {
        int e = ewave + q * 4 + rr;
        if (e < E) {
#pragma unroll
            for (int nt = 0; nt < 8; ++nt) {
                int f = nt * 16 + l15;
                P[(size_t)e * C_FEAT + f] = f2bf(acc[nt][rr] + be1[f]);
            }
        }
    }
}

// ---------------- Xab = h @ [W1a|W1b]  (N x 256, bf16) ----------------
__global__ __launch_bounds__(256) void gemm1(const float* __restrict__ h,
                                             const short* __restrict__ w1abp,
                                             short* __restrict__ Xab, int N) {
    const int tid = threadIdx.x, wave = tid >> 6, lane = tid & 63;
    const int l15 = lane & 15, q = lane >> 4;
    const int nbase = blockIdx.x * 64 + wave * 16;
    const int nr = nbase + l15;
    const int nrc = nr < N ? nr : N - 1;
    f32x4 acc[16];
#pragma unroll
    for (int nt = 0; nt < 16; ++nt) acc[nt] = (f32x4){0.f, 0.f, 0.f, 0.f};
#pragma unroll
    for (int c = 0; c < 4; ++c) {
        const float* asrc = h + (size_t)nrc * C_FEAT + c * 32 + q * 8;
        float4 a0 = ((const float4*)asrc)[0];
        float4 a1 = ((const float4*)asrc)[1];
        bf16x8 af = cvt8(a0, a1);
        const short* bb = w1abp + ((c * 4 + q) * 256) * 8;
#pragma unroll
        for (int nt = 0; nt < 16; ++nt) {
            bf16x8 bf = *(const bf16x8*)(bb + (nt * 16 + l15) * 8);
            acc[nt] = __builtin_amdgcn_mfma_f32_16x16x32_bf16(af, bf, acc[nt], 0, 0, 0);
        }
    }
#pragma unroll
    for (int rr = 0; rr < 4; ++rr) {
        int n = nbase + q * 4 + rr;
        if (n < N) {
#pragma unroll
            for (int nt = 0; nt < 16; ++nt) {
                Xab[(size_t)n * 256 + nt * 16 + l15] = f2bf(acc[nt][rr]);
            }
        }
    }
}

// ---------------- edge pass (sorted): relu(Xa[ei]+Xb[ej]+P) @ We2, merged scatter ----
__global__ __launch_bounds__(256) void edge_pass(const short* __restrict__ Xab,
                                                 const short* __restrict__ P,
                                                 const int* __restrict__ ei_s,
                                                 const int* __restrict__ ej_s,
                                                 const short* __restrict__ w2p,
                                                 const float* __restrict__ be2,
                                                 float* __restrict__ hdst, int E) {
    const int tid = threadIdx.x, wave = tid >> 6, lane = tid & 63;
    const int l15 = lane & 15, q = lane >> 4;
    const int ewave = blockIdx.x * 64 + wave * 16;
    const int eg = ewave + l15;
    const int egc = eg < E ? eg : E - 1;
    const int ni = ei_s[egc];
    const int nj = ej_s[egc];

    f32x4 acc[8];
#pragma unroll
    for (int nt = 0; nt < 8; ++nt) acc[nt] = (f32x4){0.f, 0.f, 0.f, 0.f};

#pragma unroll
    for (int c = 0; c < 4; ++c) {
        bf16x8 xa = *(const bf16x8*)(Xab + (size_t)ni * 256 + c * 32 + q * 8);
        bf16x8 xb = *(const bf16x8*)(Xab + (size_t)nj * 256 + 128 + c * 32 + q * 8);
        bf16x8 pp = *(const bf16x8*)(P + (size_t)egc * C_FEAT + c * 32 + q * 8);
        bf16x8 af;
#pragma unroll
        for (int j = 0; j < 8; ++j) {
            float z = b2f(xa[j]) + b2f(xb[j]) + b2f(pp[j]);
            af[j] = f2bf(z > 0.f ? z : 0.f);
        }
        const short* bb = w2p + ((c * 4 + q) * C_FEAT) * 8;
#pragma unroll
        for (int nt = 0; nt < 8; ++nt) {
            bf16x8 bf = *(const bf16x8*)(bb + (nt * 16 + l15) * 8);
            acc[nt] = __builtin_amdgcn_mfma_f32_16x16x32_bf16(af, bf, acc[nt], 0, 0, 0);
        }
    }

    float b2v[8];
#pragma unroll
    for (int nt = 0; nt < 8; ++nt) b2v[nt] = be2[nt * 16 + l15];

    // in-lane run merge over the 4 consecutive sorted edges this lane scatters
    int cur = -1;
    float vs[8];
#pragma unroll
    for (int rr = 0; rr < 4; ++rr) {
        int e = ewave + q * 4 + rr;
        if (e < E) {
            int tn = ej_s[e];
            if (tn == cur) {
#pragma unroll
                for (int nt = 0; nt < 8; ++nt) vs[nt] += acc[nt][rr] + b2v[nt];
            } else {
                if (cur >= 0) {
                    float* dst = hdst + (size_t)cur * C_FEAT;
#pragma unroll
                    for (int nt = 0; nt < 8; ++nt)
                        unsafeAtomicAdd(dst + nt * 16 + l15, vs[nt]);
                }
                cur = tn;
#pragma unroll
                for (int nt = 0; nt < 8; ++nt) vs[nt] = acc[nt][rr] + b2v[nt];
            }
        }
    }
    if (cur >= 0) {
        float* dst = hdst + (size_t)cur * C_FEAT;
#pragma unroll
        for (int nt = 0; nt < 8; ++nt)
            unsafeAtomicAdd(dst + nt * 16 + l15, vs[nt]);
    }
}

// ---------------- elementwise helpers ----------------
__global__ void copy_f4(const float4* __restrict__ s, float4* __restrict__ d, int n4) {
    int i = blockIdx.x * 256 + threadIdx.x;
    if (i < n4) d[i] = s[i];
}
__global__ void bias_copy(const float4* __restrict__ s, const float* __restrict__ bias,
                          float4* __restrict__ d, int n4) {
    int i = blockIdx.x * 256 + threadIdx.x;
    if (i < n4) {
        float4 v = s[i];
        float4 b = ((const float4*)bias)[i & 31];
        d[i] = make_float4(v.x + b.x, v.y + b.y, v.z + b.z, v.w + b.w);
    }
}

// ================= round-1 fallback path (known-good) =================
__global__ void prep_w_r1(const float* __restrict__ W1, const float* __restrict__ W2,
                          short* __restrict__ w1p, short* __restrict__ w2p) {
    int idx = blockIdx.x * 256 + threadIdx.x;
    if (idx < K1 * C_FEAT) {
        int k = idx >> 7, f = idx & 127;
        w1p[(((k >> 3) * C_FEAT + f) << 3) + (k & 7)] = f2bf(W1[idx]);
    }
    if (idx < C_FEAT * C_FEAT) {
        int k = idx >> 7, f = idx & 127;
        w2p[(((k >> 3) * C_FEAT + f) << 3) + (k & 7)] = f2bf(W2[idx]);
    }
}
__global__ __launch_bounds__(256) void edge_mlp_r1(
    const float* __restrict__ h, float* __restrict__ hdst,
    const int* __restrict__ ei, const int* __restrict__ ej,
    const float* __restrict__ ea,
    const short* __restrict__ w1p, const float* __restrict__ be1,
    const short* __restrict__ w2p, const float* __restrict__ be2, int E) {
    __shared__ short Hs[64][136];
    const int tid = threadIdx.x, wave = tid >> 6, lane = tid & 63;
    const int l15 = lane & 15, q = lane >> 4;
    const int ewave = blockIdx.x * 64 + wave * 16;
    const int eg = ewave + l15;
    const int egc = eg < E ? eg : E - 1;
    const int ni = ei[egc], nj = ej[egc];
    f32x4 acc[8];
#pragma unroll
    for (int nt = 0; nt < 8; ++nt) acc[nt] = (f32x4){0.f, 0.f, 0.f, 0.f};
#pragma unroll
    for (int c = 0; c < 9; ++c) {
        const float* asrc;
        if (c < 4)      asrc = h + (size_t)ni * C_FEAT + c * 32 + q * 8;
        else if (c < 8) asrc = h + (size_t)nj * C_FEAT + (c - 4) * 32 + q * 8;
        else            asrc = ea + (size_t)egc * C_EDGE + q * 8;
        float4 a0 = ((const float4*)asrc)[0];
        float4 a1 = ((const float4*)asrc)[1];
        bf16x8 af = cvt8(a0, a1);
        const short* bb = w1p + ((c * 4 + q) * C_FEAT) * 8;
#pragma unroll
        for (int nt = 0; nt < 8; ++nt) {
            bf16x8 bf = *(const bf16x8*)(bb + (nt * 16 + l15) * 8);
            acc[nt] = __builtin_amdgcn_mfma_f32_16x16x32_bf16(af, bf, acc[nt], 0, 0, 0);
        }
    }
#pragma unroll
    for (int nt = 0; nt < 8; ++nt) {
        int f = nt * 16 + l15;
        float b = be1[f];
#pragma unroll
        for (int r = 0; r < 4; ++r) {
            float v = acc[nt][r] + b;
            Hs[wave * 16 + q * 4 + r][f] = f2bf(v > 0.f ? v : 0.f);
        }
    }
    __syncthreads();
    f32x4 acc2[8];
#pragma unroll
    for (int nt = 0; nt < 8; ++nt) acc2[nt] = (f32x4){0.f, 0.f, 0.f, 0.f};
#pragma unroll
    for (int c = 0; c < 4; ++c) {
        bf16x8 af = *(const bf16x8*)(&Hs[wave * 16 + l15][c * 32 + q * 8]);
        const short* bb = w2p + ((c * 4 + q) * C_FEAT) * 8;
#pragma unroll
        for (int nt = 0; nt < 8; ++nt) {
            bf16x8 bf = *(const bf16x8*)(bb + (nt * 16 + l15) * 8);
            acc2[nt] = __builtin_amdgcn_mfma_f32_16x16x32_bf16(af, bf, acc2[nt], 0, 0, 0);
        }
    }
    float b2v[8];
#pragma unroll
    for (int nt = 0; nt < 8; ++nt) b2v[nt] = be2[nt * 16 + l15];
#pragma unroll
    for (int r = 0; r < 4; ++r) {
        int e = ewave + q * 4 + r;
        if (e < E) {
            int tn = ej[e];
            float* dst = hdst + (size_t)tn * C_FEAT;
#pragma unroll
            for (int nt = 0; nt < 8; ++nt)
                unsafeAtomicAdd(dst + nt * 16 + l15, acc2[nt][r] + b2v[nt]);
        }
    }
}

static inline size_t al256(size_t x) { return (x + 255) & ~(size_t)255; }

extern "C" void kernel_launch(void* const* d_in, const int* in_sizes, int n_in,
                              void* d_out, int out_size, void* d_ws, size_t ws_size,
                              hipStream_t stream) {
    const float* x    = (const float*)d_in[0];
    const int*   eidx = (const int*)  d_in[1];
    const float* ea   = (const float*)d_in[2];
    const float* We1  = (const float*)d_in[3];
    const float* be1  = (const float*)d_in[4];
    const float* We2  = (const float*)d_in[5];
    const float* be2  = (const float*)d_in[6];
    const float* bias = (const float*)d_in[7];
    float* out = (float*)d_out;

    const int E = in_sizes[1] / 2;
    const int N = in_sizes[0] / C_FEAT;
    const int* ei = eidx;
    const int* ej = eidx + E;

    const int n4 = N * C_FEAT / 4;
    const int cb = (n4 + 255) / 256;
    const int eb = (E + 63) / 64;

    // ---- workspace layout (new path) ----
    size_t off = 0;
    size_t o_w1abp = off; off = al256(off + (size_t)128 * 256 * 2);
    size_t o_w1cp  = off; off = al256(off + (size_t)32 * 128 * 2);
    size_t o_w2p   = off; off = al256(off + (size_t)128 * 128 * 2);
    size_t o_hist  = off; off = al256(off + (size_t)N * 4);
    size_t o_part  = off; off = al256(off + (size_t)4096);
    size_t o_woff  = off; off = al256(off + (size_t)N * 4);
    size_t o_eis   = off; off = al256(off + (size_t)E * 4);
    size_t o_ejs   = off; off = al256(off + (size_t)E * 4);
    size_t o_eperm = off; off = al256(off + (size_t)E * 4);
    size_t o_xab   = off; off = al256(off + (size_t)N * 256 * 2);
    size_t o_p     = off; off = al256(off + (size_t)E * C_FEAT * 2);
    const size_t need = off;

    if (ws_size >= need) {
        char* ws = (char*)d_ws;
        short* w1abp = (short*)(ws + o_w1abp);
        short* w1cp  = (short*)(ws + o_w1cp);
        short* w2p   = (short*)(ws + o_w2p);
        int* hist    = (int*)(ws + o_hist);
        int* part    = (int*)(ws + o_part);
        int* woff    = (int*)(ws + o_woff);
        int* ei_s    = (int*)(ws + o_eis);
        int* ej_s    = (int*)(ws + o_ejs);
        int* eperm   = (int*)(ws + o_eperm);
        short* Xab   = (short*)(ws + o_xab);
        short* P     = (short*)(ws + o_p);

        const int nbScan = (N + 511) / 512;

        prep_w2<<<128, 256, 0, stream>>>(We1, We2, w1abp, w1cp, w2p);
        // counting sort by ej
        k_zero<<<(N + 255) / 256, 256, 0, stream>>>(hist, N);
        k_hist<<<(E + 255) / 256, 256, 0, stream>>>(ej, hist, E);
        k_red<<<nbScan, 512, 0, stream>>>(hist, part, N);
        k_scanpart<<<1, 64, 0, stream>>>(part, nbScan);
        k_scanblk<<<nbScan, 512, 0, stream>>>(hist, part, woff, N);
        k_perm<<<(E + 255) / 256, 256, 0, stream>>>(ei, ej, woff, ei_s, ej_s, eperm, E);
        // P = ea@W1c + be1 (sorted, constant across steps)
        p_mfma<<<eb, 256, 0, stream>>>(ea, eperm, w1cp, be1, P, E);

        // step 1: d_out = x + scatter(m1)
        gemm1<<<(N + 63) / 64, 256, 0, stream>>>(x, w1abp, Xab, N);
        copy_f4<<<cb, 256, 0, stream>>>((const float4*)x, (float4*)out, n4);
        edge_pass<<<eb, 256, 0, stream>>>(Xab, P, ei_s, ej_s, w2p, be2, out, E);
        // step 2: d_out = h1 + bias + scatter(m2)
        gemm1<<<(N + 63) / 64, 256, 0, stream>>>(out, w1abp, Xab, N);
        bias_copy<<<cb, 256, 0, stream>>>((const float4*)out, bias, (float4*)out, n4);
        edge_pass<<<eb, 256, 0, stream>>>(Xab, P, ei_s, ej_s, w2p, be2, out, E);
    } else {
        // round-1 known-good fallback
        float* bufA = (float*)d_ws;
        short* w1p  = (short*)((char*)d_ws + (size_t)N * C_FEAT * sizeof(float));
        short* w2p  = w1p + K1 * C_FEAT;
        prep_w_r1<<<144, 256, 0, stream>>>(We1, We2, w1p, w2p);
        copy_f4<<<cb, 256, 0, stream>>>((const float4*)x, (float4*)bufA, n4);
        edge_mlp_r1<<<eb, 256, 0, stream>>>(x, bufA, ei, ej, ea, w1p, be1, w2p, be2, E);
        bias_copy<<<cb, 256, 0, stream>>>((const float4*)bufA, bias, (float4*)out, n4);
        edge_mlp_r1<<<eb, 256, 0, stream>>>(bufA, out, ei, ej, ea, w1p, be1, w2p, be2, E);
    }
}

// Round 3
// 644.160 us; speedup vs baseline: 1.0782x; 1.0782x over previous
//
#include <hip/hip_runtime.h>

#define C_FEAT 128
#define C_EDGE 32
#define K1 288

typedef __attribute__((ext_vector_type(8))) short bf16x8;
typedef __attribute__((ext_vector_type(4))) float f32x4;

__device__ __forceinline__ short f2bf(float x) {
    union { float f; unsigned u; } v; v.f = x;
    unsigned r = v.u + 0x7fffu + ((v.u >> 16) & 1u);   // RTN-even
    return (short)(r >> 16);
}
__device__ __forceinline__ float b2f(short s) {
    union { float f; unsigned u; } v; v.u = ((unsigned)(unsigned short)s) << 16;
    return v.f;
}
__device__ __forceinline__ bf16x8 cvt8(float4 a, float4 b) {
    bf16x8 r;
    r[0] = f2bf(a.x); r[1] = f2bf(a.y); r[2] = f2bf(a.z); r[3] = f2bf(a.w);
    r[4] = f2bf(b.x); r[5] = f2bf(b.y); r[6] = f2bf(b.z); r[7] = f2bf(b.w);
    return r;
}

// ---------------- weight packing ----------------
// B-fragment layout: wp[((k>>3)*F + f)*8 + (k&7)] -> 8 consecutive k for fixed
// f is one 16B load per lane.
__global__ void prep_w2(const float* __restrict__ We1, const float* __restrict__ We2,
                        short* __restrict__ w1abp, short* __restrict__ w1cp,
                        short* __restrict__ w2p) {
    int idx = blockIdx.x * 256 + threadIdx.x;
    if (idx < 128 * 256) {              // [W1a | W1b]: K=128, F=256
        int k = idx >> 8, f = idx & 255;
        float v = (f < 128) ? We1[k * 128 + f] : We1[(128 + k) * 128 + (f - 128)];
        w1abp[(((k >> 3) * 256 + f) << 3) + (k & 7)] = f2bf(v);
    }
    if (idx < 32 * 128) {               // W1c: K=32, F=128
        int k = idx >> 7, f = idx & 127;
        w1cp[(((k >> 3) * 128 + f) << 3) + (k & 7)] = f2bf(We1[(256 + k) * 128 + f]);
    }
    if (idx < 128 * 128) {              // We2
        int k = idx >> 7, f = idx & 127;
        w2p[(((k >> 3) * 128 + f) << 3) + (k & 7)] = f2bf(We2[k * 128 + f]);
    }
}

// ---------------- counting sort by ej (hist zeroed via memsetAsync) -------
__global__ void k_hist(const int* __restrict__ ej, int* __restrict__ hist, int E) {
    int e = blockIdx.x * 256 + threadIdx.x;
    if (e < E) atomicAdd(&hist[ej[e]], 1);
}
__global__ void k_red(const int* __restrict__ hist, int* __restrict__ part, int N) {
    __shared__ int s[512];
    int t = threadIdx.x, i = blockIdx.x * 512 + t;
    s[t] = i < N ? hist[i] : 0;
    __syncthreads();
    for (int o = 256; o > 0; o >>= 1) {
        if (t < o) s[t] += s[t + o];
        __syncthreads();
    }
    if (t == 0) part[blockIdx.x] = s[0];
}
__global__ void k_scanpart(int* __restrict__ part, int nb) {
    if (threadIdx.x == 0 && blockIdx.x == 0) {
        int a = 0;
        for (int i = 0; i < nb; ++i) { int v = part[i]; part[i] = a; a += v; }
    }
}
__global__ void k_scanblk(const int* __restrict__ hist, const int* __restrict__ part,
                          int* __restrict__ woff, int N) {
    __shared__ int s[512];
    int t = threadIdx.x, i = blockIdx.x * 512 + t;
    int v = i < N ? hist[i] : 0;
    s[t] = v;
    __syncthreads();
    for (int o = 1; o < 512; o <<= 1) {
        int x = (t >= o) ? s[t - o] : 0;
        __syncthreads();
        s[t] += x;
        __syncthreads();
    }
    if (i < N) woff[i] = part[blockIdx.x] + s[t] - v;   // exclusive
}
// permute edges into ej-sorted order; fuse ea gather+bf16 convert (sequential
// read of ea here, so no random f32 gather is ever needed later).
__global__ void k_perm(const int* __restrict__ ei, const int* __restrict__ ej,
                       const float* __restrict__ ea, int* __restrict__ woff,
                       int* __restrict__ ei_s, int* __restrict__ ej_s,
                       short* __restrict__ ea_s, int E) {
    int e = blockIdx.x * 256 + threadIdx.x;
    if (e < E) {
        int t = ej[e];
        int pos = atomicAdd(&woff[t], 1);
        ei_s[pos] = ei[e];
        ej_s[pos] = t;
        const float4* src = (const float4*)(ea + (size_t)e * C_EDGE);
        short* dst = ea_s + (size_t)pos * C_EDGE;
#pragma unroll
        for (int c = 0; c < 4; ++c) {
            float4 a0 = src[2 * c], a1 = src[2 * c + 1];
            bf16x8 v = cvt8(a0, a1);
            *(bf16x8*)(dst + c * 8) = v;
        }
    }
}

// ---------------- Xab = h @ [W1a|W1b]  (N x 256, bf16) ----------------
__global__ __launch_bounds__(256) void gemm1(const float* __restrict__ h,
                                             const short* __restrict__ w1abp,
                                             short* __restrict__ Xab, int N) {
    const int tid = threadIdx.x, wave = tid >> 6, lane = tid & 63;
    const int l15 = lane & 15, q = lane >> 4;
    const int nbase = blockIdx.x * 64 + wave * 16;
    const int nr = nbase + l15;
    const int nrc = nr < N ? nr : N - 1;
    f32x4 acc[16];
#pragma unroll
    for (int nt = 0; nt < 16; ++nt) acc[nt] = (f32x4){0.f, 0.f, 0.f, 0.f};
#pragma unroll
    for (int c = 0; c < 4; ++c) {
        const float* asrc = h + (size_t)nrc * C_FEAT + c * 32 + q * 8;
        float4 a0 = ((const float4*)asrc)[0];
        float4 a1 = ((const float4*)asrc)[1];
        bf16x8 af = cvt8(a0, a1);
        const short* bb = w1abp + ((c * 4 + q) * 256) * 8;
#pragma unroll
        for (int nt = 0; nt < 16; ++nt) {
            bf16x8 bf = *(const bf16x8*)(bb + (nt * 16 + l15) * 8);
            acc[nt] = __builtin_amdgcn_mfma_f32_16x16x32_bf16(af, bf, acc[nt], 0, 0, 0);
        }
    }
#pragma unroll
    for (int rr = 0; rr < 4; ++rr) {
        int n = nbase + q * 4 + rr;
        if (n < N) {
#pragma unroll
            for (int nt = 0; nt < 16; ++nt) {
                Xab[(size_t)n * 256 + nt * 16 + l15] = f2bf(acc[nt][rr]);
            }
        }
    }
}

// ---- edge pass: relu(Xa[ei]+Xb[ej]+ea@W1c+be1) @ We2 + be2, merged scatter ----
// 32 edges per wave (two 16-row m-tiles) for 2x outstanding gathers.
#define ZSTRIDE 136
__global__ __launch_bounds__(256) void edge_pass(const short* __restrict__ Xab,
                                                 const short* __restrict__ ea_s,
                                                 const int* __restrict__ ei_s,
                                                 const int* __restrict__ ej_s,
                                                 const short* __restrict__ w1cp,
                                                 const float* __restrict__ be1,
                                                 const short* __restrict__ w2p,
                                                 const float* __restrict__ be2,
                                                 float* __restrict__ hdst, int E) {
    __shared__ short Z[4][2][16 * ZSTRIDE];   // [wave][tile][m*136+f] ~ 34.8 KB
    const int tid = threadIdx.x, wave = tid >> 6, lane = tid & 63;
    const int l15 = lane & 15, q = lane >> 4;
    const int base = blockIdx.x * 128 + wave * 32;

    int ni[2], nj[2], egc[2];
#pragma unroll
    for (int t = 0; t < 2; ++t) {
        int eg = base + t * 16 + l15;
        egc[t] = eg < E ? eg : E - 1;
        ni[t] = ei_s[egc[t]];
        nj[t] = ej_s[egc[t]];
    }

    // ---- z = ea @ W1c + be1, per tile, via MFMA + wave-local LDS transpose ----
#pragma unroll
    for (int t = 0; t < 2; ++t) {
        bf16x8 af = *(const bf16x8*)(ea_s + (size_t)egc[t] * C_EDGE + q * 8);
        f32x4 accP[8];
#pragma unroll
        for (int nt = 0; nt < 8; ++nt) {
            bf16x8 bf = *(const bf16x8*)(w1cp + ((q * C_FEAT + nt * 16 + l15) << 3));
            accP[nt] = __builtin_amdgcn_mfma_f32_16x16x32_bf16(
                af, bf, (f32x4){0.f, 0.f, 0.f, 0.f}, 0, 0, 0);
        }
        short* zw = &Z[wave][t][0];
#pragma unroll
        for (int nt = 0; nt < 8; ++nt) {
            int f = nt * 16 + l15;
            float b = be1[f];
#pragma unroll
            for (int r = 0; r < 4; ++r) {
                zw[(q * 4 + r) * ZSTRIDE + f] = f2bf(accP[nt][r] + b);
            }
        }
    }
    __syncthreads();

    f32x4 acc[2][8];
#pragma unroll
    for (int t = 0; t < 2; ++t)
#pragma unroll
        for (int nt = 0; nt < 8; ++nt) acc[t][nt] = (f32x4){0.f, 0.f, 0.f, 0.f};

    // ---- layer 2: K=128, share B-fragments across the two tiles ----
#pragma unroll
    for (int c = 0; c < 4; ++c) {
        bf16x8 bfr[8];
        const short* bb = w2p + ((c * 4 + q) * C_FEAT) * 8;
#pragma unroll
        for (int nt = 0; nt < 8; ++nt)
            bfr[nt] = *(const bf16x8*)(bb + (nt * 16 + l15) * 8);
#pragma unroll
        for (int t = 0; t < 2; ++t) {
            bf16x8 xa = *(const bf16x8*)(Xab + (size_t)ni[t] * 256 + c * 32 + q * 8);
            bf16x8 xb = *(const bf16x8*)(Xab + (size_t)nj[t] * 256 + 128 + c * 32 + q * 8);
            bf16x8 zz = *(const bf16x8*)(&Z[wave][t][l15 * ZSTRIDE + c * 32 + q * 8]);
            bf16x8 af;
#pragma unroll
            for (int j = 0; j < 8; ++j) {
                float z = b2f(xa[j]) + b2f(xb[j]) + b2f(zz[j]);
                af[j] = f2bf(z > 0.f ? z : 0.f);
            }
#pragma unroll
            for (int nt = 0; nt < 8; ++nt)
                acc[t][nt] = __builtin_amdgcn_mfma_f32_16x16x32_bf16(af, bfr[nt],
                                                                     acc[t][nt], 0, 0, 0);
        }
    }

    float b2v[8];
#pragma unroll
    for (int nt = 0; nt < 8; ++nt) b2v[nt] = be2[nt * 16 + l15];

    // ---- + be2, in-lane run-merged scatter (edges sorted by target) ----
#pragma unroll
    for (int t = 0; t < 2; ++t) {
        int cur = -1;
        float vs[8];
#pragma unroll
        for (int rr = 0; rr < 4; ++rr) {
            int e = base + t * 16 + q * 4 + rr;
            if (e < E) {
                int tn = ej_s[e];
                if (tn == cur) {
#pragma unroll
                    for (int nt = 0; nt < 8; ++nt) vs[nt] += acc[t][nt][rr] + b2v[nt];
                } else {
                    if (cur >= 0) {
                        float* dst = hdst + (size_t)cur * C_FEAT;
#pragma unroll
                        for (int nt = 0; nt < 8; ++nt)
                            unsafeAtomicAdd(dst + nt * 16 + l15, vs[nt]);
                    }
                    cur = tn;
#pragma unroll
                    for (int nt = 0; nt < 8; ++nt) vs[nt] = acc[t][nt][rr] + b2v[nt];
                }
            }
        }
        if (cur >= 0) {
            float* dst = hdst + (size_t)cur * C_FEAT;
#pragma unroll
            for (int nt = 0; nt < 8; ++nt)
                unsafeAtomicAdd(dst + nt * 16 + l15, vs[nt]);
        }
    }
}

// ---------------- elementwise helpers ----------------
__global__ void copy_f4(const float4* __restrict__ s, float4* __restrict__ d, int n4) {
    int i = blockIdx.x * 256 + threadIdx.x;
    if (i < n4) d[i] = s[i];
}
__global__ void bias_copy(const float4* __restrict__ s, const float* __restrict__ bias,
                          float4* __restrict__ d, int n4) {
    int i = blockIdx.x * 256 + threadIdx.x;
    if (i < n4) {
        float4 v = s[i];
        float4 b = ((const float4*)bias)[i & 31];
        d[i] = make_float4(v.x + b.x, v.y + b.y, v.z + b.z, v.w + b.w);
    }
}

// ================= round-1 fallback path (known-good) =================
__global__ void prep_w_r1(const float* __restrict__ W1, const float* __restrict__ W2,
                          short* __restrict__ w1p, short* __restrict__ w2p) {
    int idx = blockIdx.x * 256 + threadIdx.x;
    if (idx < K1 * C_FEAT) {
        int k = idx >> 7, f = idx & 127;
        w1p[(((k >> 3) * C_FEAT + f) << 3) + (k & 7)] = f2bf(W1[idx]);
    }
    if (idx < C_FEAT * C_FEAT) {
        int k = idx >> 7, f = idx & 127;
        w2p[(((k >> 3) * C_FEAT + f) << 3) + (k & 7)] = f2bf(W2[idx]);
    }
}
__global__ __launch_bounds__(256) void edge_mlp_r1(
    const float* __restrict__ h, float* __restrict__ hdst,
    const int* __restrict__ ei, const int* __restrict__ ej,
    const float* __restrict__ ea,
    const short* __restrict__ w1p, const float* __restrict__ be1,
    const short* __restrict__ w2p, const float* __restrict__ be2, int E) {
    __shared__ short Hs[64][136];
    const int tid = threadIdx.x, wave = tid >> 6, lane = tid & 63;
    const int l15 = lane & 15, q = lane >> 4;
    const int ewave = blockIdx.x * 64 + wave * 16;
    const int eg = ewave + l15;
    const int egc = eg < E ? eg : E - 1;
    const int ni = ei[egc], nj = ej[egc];
    f32x4 acc[8];
#pragma unroll
    for (int nt = 0; nt < 8; ++nt) acc[nt] = (f32x4){0.f, 0.f, 0.f, 0.f};
#pragma unroll
    for (int c = 0; c < 9; ++c) {
        const float* asrc;
        if (c < 4)      asrc = h + (size_t)ni * C_FEAT + c * 32 + q * 8;
        else if (c < 8) asrc = h + (size_t)nj * C_FEAT + (c - 4) * 32 + q * 8;
        else            asrc = ea + (size_t)egc * C_EDGE + q * 8;
        float4 a0 = ((const float4*)asrc)[0];
        float4 a1 = ((const float4*)asrc)[1];
        bf16x8 af = cvt8(a0, a1);
        const short* bb = w1p + ((c * 4 + q) * C_FEAT) * 8;
#pragma unroll
        for (int nt = 0; nt < 8; ++nt) {
            bf16x8 bf = *(const bf16x8*)(bb + (nt * 16 + l15) * 8);
            acc[nt] = __builtin_amdgcn_mfma_f32_16x16x32_bf16(af, bf, acc[nt], 0, 0, 0);
        }
    }
#pragma unroll
    for (int nt = 0; nt < 8; ++nt) {
        int f = nt * 16 + l15;
        float b = be1[f];
#pragma unroll
        for (int r = 0; r < 4; ++r) {
            float v = acc[nt][r] + b;
            Hs[wave * 16 + q * 4 + r][f] = f2bf(v > 0.f ? v : 0.f);
        }
    }
    __syncthreads();
    f32x4 acc2[8];
#pragma unroll
    for (int nt = 0; nt < 8; ++nt) acc2[nt] = (f32x4){0.f, 0.f, 0.f, 0.f};
#pragma unroll
    for (int c = 0; c < 4; ++c) {
        bf16x8 af = *(const bf16x8*)(&Hs[wave * 16 + l15][c * 32 + q * 8]);
        const short* bb = w2p + ((c * 4 + q) * C_FEAT) * 8;
#pragma unroll
        for (int nt = 0; nt < 8; ++nt) {
            bf16x8 bf = *(const bf16x8*)(bb + (nt * 16 + l15) * 8);
            acc2[nt] = __builtin_amdgcn_mfma_f32_16x16x32_bf16(af, bf, acc2[nt], 0, 0, 0);
        }
    }
    float b2v[8];
#pragma unroll
    for (int nt = 0; nt < 8; ++nt) b2v[nt] = be2[nt * 16 + l15];
#pragma unroll
    for (int r = 0; r < 4; ++r) {
        int e = ewave + q * 4 + r;
        if (e < E) {
            int tn = ej[e];
            float* dst = hdst + (size_t)tn * C_FEAT;
#pragma unroll
            for (int nt = 0; nt < 8; ++nt)
                unsafeAtomicAdd(dst + nt * 16 + l15, acc2[nt][r] + b2v[nt]);
        }
    }
}

static inline size_t al256(size_t x) { return (x + 255) & ~(size_t)255; }

extern "C" void kernel_launch(void* const* d_in, const int* in_sizes, int n_in,
                              void* d_out, int out_size, void* d_ws, size_t ws_size,
                              hipStream_t stream) {
    const float* x    = (const float*)d_in[0];
    const int*   eidx = (const int*)  d_in[1];
    const float* ea   = (const float*)d_in[2];
    const float* We1  = (const float*)d_in[3];
    const float* be1  = (const float*)d_in[4];
    const float* We2  = (const float*)d_in[5];
    const float* be2  = (const float*)d_in[6];
    const float* bias = (const float*)d_in[7];
    float* out = (float*)d_out;

    const int E = in_sizes[1] / 2;
    const int N = in_sizes[0] / C_FEAT;
    const int* ei = eidx;
    const int* ej = eidx + E;

    const int n4 = N * C_FEAT / 4;
    const int cb = (n4 + 255) / 256;
    const int eb2 = (E + 127) / 128;

    // ---- workspace layout ----
    size_t off = 0;
    size_t o_w1abp = off; off = al256(off + (size_t)128 * 256 * 2);
    size_t o_w1cp  = off; off = al256(off + (size_t)32 * 128 * 2);
    size_t o_w2p   = off; off = al256(off + (size_t)128 * 128 * 2);
    size_t o_hist  = off; off = al256(off + (size_t)N * 4);
    size_t o_part  = off; off = al256(off + (size_t)4096);
    size_t o_woff  = off; off = al256(off + (size_t)N * 4);
    size_t o_eis   = off; off = al256(off + (size_t)E * 4);
    size_t o_ejs   = off; off = al256(off + (size_t)E * 4);
    size_t o_eas   = off; off = al256(off + (size_t)E * C_EDGE * 2);
    size_t o_xab   = off; off = al256(off + (size_t)N * 256 * 2);
    const size_t need = off;

    if (ws_size >= need) {
        char* ws = (char*)d_ws;
        short* w1abp = (short*)(ws + o_w1abp);
        short* w1cp  = (short*)(ws + o_w1cp);
        short* w2p   = (short*)(ws + o_w2p);
        int* hist    = (int*)(ws + o_hist);
        int* part    = (int*)(ws + o_part);
        int* woff    = (int*)(ws + o_woff);
        int* ei_s    = (int*)(ws + o_eis);
        int* ej_s    = (int*)(ws + o_ejs);
        short* ea_s  = (short*)(ws + o_eas);
        short* Xab   = (short*)(ws + o_xab);

        const int nbScan = (N + 511) / 512;

        prep_w2<<<128, 256, 0, stream>>>(We1, We2, w1abp, w1cp, w2p);
        // counting sort by ej (+ fused ea permute/convert)
        hipMemsetAsync(hist, 0, (size_t)N * 4, stream);
        k_hist<<<(E + 255) / 256, 256, 0, stream>>>(ej, hist, E);
        k_red<<<nbScan, 512, 0, stream>>>(hist, part, N);
        k_scanpart<<<1, 64, 0, stream>>>(part, nbScan);
        k_scanblk<<<nbScan, 512, 0, stream>>>(hist, part, woff, N);
        k_perm<<<(E + 255) / 256, 256, 0, stream>>>(ei, ej, ea, woff, ei_s, ej_s, ea_s, E);

        // step 1: out = x + scatter(m1)
        gemm1<<<(N + 63) / 64, 256, 0, stream>>>(x, w1abp, Xab, N);
        copy_f4<<<cb, 256, 0, stream>>>((const float4*)x, (float4*)out, n4);
        edge_pass<<<eb2, 256, 0, stream>>>(Xab, ea_s, ei_s, ej_s, w1cp, be1, w2p, be2, out, E);
        // step 2: out = h1 + bias + scatter(m2)
        gemm1<<<(N + 63) / 64, 256, 0, stream>>>(out, w1abp, Xab, N);
        bias_copy<<<cb, 256, 0, stream>>>((const float4*)out, bias, (float4*)out, n4);
        edge_pass<<<eb2, 256, 0, stream>>>(Xab, ea_s, ei_s, ej_s, w1cp, be1, w2p, be2, out, E);
    } else {
        // round-1 known-good fallback
        const int eb = (E + 63) / 64;
        float* bufA = (float*)d_ws;
        short* w1p  = (short*)((char*)d_ws + (size_t)N * C_FEAT * sizeof(float));
        short* w2p  = w1p + K1 * C_FEAT;
        prep_w_r1<<<144, 256, 0, stream>>>(We1, We2, w1p, w2p);
        copy_f4<<<cb, 256, 0, stream>>>((const float4*)x, (float4*)bufA, n4);
        edge_mlp_r1<<<eb, 256, 0, stream>>>(x, bufA, ei, ej, ea, w1p, be1, w2p, be2, E);
        bias_copy<<<cb, 256, 0, stream>>>((const float4*)bufA, bias, (float4*)out, n4);
        edge_mlp_r1<<<eb, 256, 0, stream>>>(bufA, out, ei, ej, ea, w1p, be1, w2p, be2, E);
    }
}